// Round 7
// baseline (172.210 us; speedup 1.0000x reference)
//
#include <hip/hip_runtime.h>

namespace {

typedef __bf16 bf16x8 __attribute__((ext_vector_type(8)));
typedef float f32x4 __attribute__((ext_vector_type(4)));
typedef unsigned int uint4v __attribute__((ext_vector_type(4)));

#define MFMA16(a,b,c) __builtin_amdgcn_mfma_f32_16x16x32_bf16((a),(b),(c),0,0,0)

constexpr float SCALE = 0.125f;   // 1/sqrt(64)

// ---------------- ws layout (all bf16 tiles COLUMN-pi-packed, plain row-major;
// read directly from global as MFMA fragments) ----------------
// slots i*8192, i=0..6: 0 embed, 1 M0T, 2 Wvo, 3 M1T, 4 Nw1, 5 M2T, 6 Nw2
constexpr int WS_HW  = 57344;  // head weights [16][128] bf16 (pi per 64-half), 4096 B
constexpr int WS_NV  = 61440;  // Nv tile [16][64] bf16 (rows 0-3 used), 2048 B
constexpr int WS_VEC = 63488;  // f32 vecs: m0,cc,wt1,wt2,d1,e1,d2,e2 (8 x 64)
constexpr int WS_SC  = 65536;  // f32 scalars: c1, hbk1, c2, hbk2

__device__ __forceinline__ int PI(int c){ return 4*(c&15) + (c>>4); }
__device__ __forceinline__ int PINV(int p){ return 16*(p&3) + (p>>2); }

__device__ __forceinline__ unsigned short f2b(float f){
  return __builtin_bit_cast(unsigned short, (__bf16)f);
}
__device__ __forceinline__ unsigned pack2(float a, float b){
  return (unsigned)f2b(a) | ((unsigned)f2b(b)<<16);
}
template<int ACT>  // 0 none, 1 leaky-relu(0.2), 2 tanh
__device__ __forceinline__ float actf(float v){
  if constexpr (ACT==1) return v>0.f ? v : 0.2f*v;
  else if constexpr (ACT==2) return 1.f - 2.f/(__expf(2.f*v)+1.f);
  else return v;
}

// ---------------- prep kernel (identical to round-4, proven) ----------------
struct PrepP {
  const float *embed_w, *mean_w, *ls_w;
  const float *ia_wq, *ia_bq, *ia_wk, *ia_wv, *ia_wo, *ia_bv, *ia_bo;
  const float *c1_wq, *c1_bq, *c1_wk, *c1_bk, *c1_wv, *c1_bv, *c1_wo, *c1_bo;
  const float *c2_wq, *c2_bq, *c2_wk, *c2_bk, *c2_wv, *c2_bv, *c2_wo, *c2_bo;
  const float *msg_w, *msg_b, *st_w, *st_b;
  char* ws;
};

__device__ void mmAB_f32(const float* A, const float* B, float* O){
  const int t=threadIdx.x, r=t>>2, c0=(t&3)*16;
  float acc[16];
  #pragma unroll
  for(int j=0;j<16;j++) acc[j]=0.f;
  for(int h=0;h<64;h++){
    const float a=A[r*64+h];
    #pragma unroll
    for(int j=0;j<16;j++) acc[j]=fmaf(a,B[h*64+c0+j],acc[j]);
  }
  #pragma unroll
  for(int j=0;j<16;j++) O[r*64+c0+j]=acc[j];
}
__device__ void mmAB_bf(const float* A, const float* B, __bf16* D){
  const int t=threadIdx.x, r=t>>2, c0=(t&3)*16;
  float acc[16];
  #pragma unroll
  for(int j=0;j<16;j++) acc[j]=0.f;
  for(int h=0;h<64;h++){
    const float a=A[r*64+h];
    #pragma unroll
    for(int j=0;j<16;j++) acc[j]=fmaf(a,B[h*64+c0+j],acc[j]);
  }
  #pragma unroll
  for(int j=0;j<16;j++) D[r*64+PI(c0+j)]=(__bf16)acc[j];
}
__device__ void mmTA_bf(const float* A, const float* B, __bf16* D){
  const int t=threadIdx.x, a=t>>2, b0=(t&3)*16;
  float acc[16];
  #pragma unroll
  for(int j=0;j<16;j++) acc[j]=0.f;
  for(int h=0;h<64;h++){
    const float av=A[h*64+a];
    #pragma unroll
    for(int j=0;j<16;j++) acc[j]=fmaf(av,B[h*64+b0+j],acc[j]);
  }
  #pragma unroll
  for(int j=0;j<16;j++) D[a*64+PI(b0+j)]=(__bf16)acc[j];
}

__global__ void prep_kernel(PrepP q){
  __shared__ float PF[2][4096];
  __shared__ float hv[64], gv[64];
  const int job=blockIdx.x, t=threadIdx.x;
  char* ws=q.ws;
  float* VECF=(float*)(ws+WS_VEC);
  float* SCF =(float*)(ws+WS_SC);
  __bf16* NVD=(__bf16*)(ws+WS_NV);

  if(job==0){
    __bf16* emb=(__bf16*)(ws+0*8192);
    #pragma unroll
    for(int i=0;i<16;i++){
      const int idx=t*16+i, o=idx>>6, p=idx&63;
      emb[idx]=(__bf16)q.embed_w[o*64+PINV(p)];
    }
    __bf16* hw=(__bf16*)(ws+WS_HW);
    #pragma unroll
    for(int i=0;i<8;i++){
      const int flat=t*8+i, o=flat>>7, qq=flat&127, half=qq>>6, p=qq&63;
      const float v=(o<8)?q.mean_w[o*128+half*64+PINV(p)]
                         :q.ls_w[(o-8)*128+half*64+PINV(p)];
      hw[flat]=(__bf16)v;
    }
    #pragma unroll
    for(int i=0;i<3;i++){ const int id=t*3+i; if(id<768) NVD[256+id]=(__bf16)0.f; }
  } else if(job==1){
    mmTA_bf(q.ia_wk, q.ia_wq, (__bf16*)(ws+1*8192));
    if(t<64){ float s=0; for(int h=0;h<64;h++) s+=q.ia_wk[h*64+t]*q.ia_bq[h]; VECF[t]=s; }
  } else if(job==2){
    mmAB_bf(q.ia_wo, q.ia_wv, (__bf16*)(ws+2*8192));
    if(t<64){ float s=q.ia_bo[t]; for(int h=0;h<64;h++) s+=q.ia_wo[t*64+h]*q.ia_bv[h];
              VECF[64+t]=s; }
  } else if(job==3 || job==5){
    const int cons=(job==3)?0:1;
    const float *wq=cons?q.c2_wq:q.c1_wq, *bq=cons?q.c2_bq:q.c1_bq;
    const float *wk=cons?q.c2_wk:q.c1_wk, *bk=cons?q.c2_bk:q.c1_bk;
    mmAB_f32(wq, q.st_w, PF[0]);                       // G = wq@st_w
    if(t<64){ float s=bq[t]; for(int k=0;k<64;k++) s+=wq[t*64+k]*q.st_b[k]; hv[t]=s; }
    __syncthreads();
    mmAB_f32(wk, q.msg_w, PF[1]);                      // F = wk@msg_w
    if(t<64){ float s=0; for(int k=0;k<64;k++) s+=wk[t*64+k]*q.msg_b[k]; gv[t]=s; }
    __syncthreads();
    mmTA_bf(PF[1], PF[0], (__bf16*)(ws+(cons?5:3)*8192));  // M1T/M2T
    if(t<64){
      float s=0; for(int h=0;h<64;h++) s+=PF[1][h*64+t]*hv[h];
      VECF[128+cons*64+t]=s;                            // wt = F^T h
      float s0=0,s1=0;
      for(int h=0;h<64;h++){ s0+=PF[0][h*64+t]*gv[h]; s1+=PF[0][h*64+t]*bk[h]; }
      NVD[(2*cons  )*64+PI(t)]=(__bf16)s0;              // u-vec  = G^T g
      NVD[(2*cons+1)*64+PI(t)]=(__bf16)s1;              // qb-vec = G^T bk
    }
    if(t==0){
      float c=0,hb=0;
      for(int i=0;i<64;i++){ c+=hv[i]*gv[i]; hb+=hv[i]*bk[i]; }
      SCF[2*cons]=c; SCF[2*cons+1]=hb;
    }
  } else {
    const int cons=(job==4)?0:1;
    const float *wo=cons?q.c2_wo:q.c1_wo, *wvv=cons?q.c2_wv:q.c1_wv;
    const float *bv=cons?q.c2_bv:q.c1_bv, *bo=cons?q.c2_bo:q.c1_bo;
    mmAB_f32(wo, wvv, PF[0]);                          // U = wo@wv
    if(t<64){ float s=bo[t]; for(int h=0;h<64;h++) s+=wo[t*64+h]*bv[h];
              VECF[320+cons*128+t]=s; }                 // e = wo@bv + bo
    __syncthreads();
    mmAB_bf(PF[0], q.msg_w, (__bf16*)(ws+(cons?6:4)*8192));  // Nw
    if(t<64){ float s=0; for(int k=0;k<64;k++) s+=PF[0][t*64+k]*q.msg_b[k];
              VECF[256+cons*128+t]=s; }                 // d = U@msg_b
  }
}

// ---------------- main kernel: one wave per batch item, zero barriers ---------
struct Params {
  const float *x, *rnd; const int *idx;
  const float *embed_b, *mean_b, *ls_b;
  const char* ws; float* out; int std_off;
};

constexpr int ITEMS = 2;   // items (waves) per block; LDS = 2*25.5KB = 51KB

// LDS tile fragment read (XOR-swizzled rows, 16B, conflict-free)
__device__ __forceinline__ bf16x8 fragld(const char* buf, int row, int kb){
  const int byte = row*128 + (kb ^ ((row&7)<<4));
  return __builtin_bit_cast(bf16x8, *reinterpret_cast<const uint4v*>(buf + byte));
}
__device__ __forceinline__ bf16x8 gld(const char* a){
  return __builtin_bit_cast(bf16x8, *reinterpret_cast<const uint4v*>(a));
}
__device__ __forceinline__ void loadB_lds(const char* Bl, bf16x8* bf, int fr, int fg){
  #pragma unroll
  for(int n=0;n<4;n++){
    bf[2*n]   = fragld(Bl, n*16+fr, fg*16);
    bf[2*n+1] = fragld(Bl, n*16+fr, 64+fg*16);
  }
}
__device__ __forceinline__ void loadB_gl(const char* W, bf16x8* bf, int fr, int fg){
  #pragma unroll
  for(int n=0;n<4;n++){
    bf[2*n]   = gld(W + (n*16+fr)*128 + fg*16);
    bf[2*n+1] = gld(W + (n*16+fr)*128 + 64 + fg*16);
  }
}

// full 64x64 matmul: C = ACT(A @ bf^T + bz[col] [+ sr[row]*dd[col]]), per-row-tile
// streamed (in-place A==C safe: each rt's reads precede its stores; later rts
// touch different rows). A from LDS (AG=0) or global (AG=1).
template<int ACT, bool AG, bool SD>
__device__ __forceinline__ void stage_mm(const char* A, const bf16x8* bf, char* C,
                                         const float* bz, const f32x4* sr,
                                         const float* dd, int fr, int fg){
  #pragma unroll
  for(int rt=0;rt<4;rt++){
    bf16x8 a0,a1;
    if constexpr(AG){
      a0=gld(A+(16*rt+fr)*128+fg*16); a1=gld(A+(16*rt+fr)*128+64+fg*16);
    } else {
      a0=fragld(A,16*rt+fr,fg*16); a1=fragld(A,16*rt+fr,64+fg*16);
    }
    f32x4 acc[4]={{0,0,0,0},{0,0,0,0},{0,0,0,0},{0,0,0,0}};
    #pragma unroll
    for(int n=0;n<4;n++){
      acc[n]=MFMA16(a0,bf[2*n],acc[n]);
      acc[n]=MFMA16(a1,bf[2*n+1],acc[n]);
    }
    #pragma unroll
    for(int r=0;r<4;r++){
      const int R=16*rt+4*fg+r;
      float v[4];
      #pragma unroll
      for(int n=0;n<4;n++){
        float x=acc[n][r]+bz[n];
        if constexpr(SD) x+=sr[rt][r]*dd[n];
        v[n]=actf<ACT>(x);
      }
      uint2 pk; pk.x=pack2(v[0],v[1]); pk.y=pack2(v[2],v[3]);
      *reinterpret_cast<uint2*>(C + R*128 + ((8*fr)^((R&7)<<4))) = pk;
    }
  }
}

// MODE 0: P=softmax(S*SCALE). MODE 1: consensus mg, emits mask bits mb[rt] and
// masked-rowsum srout. MODE 2: uses complement of mb. In-place A==P safe.
template<int MODE>
__device__ __forceinline__ void ssoft_f(const char* Aq, const char* Bk, char* P,
                                        const float2* ra, const float4* zz,
                                        float cu, float cq, f32x4* srout,
                                        unsigned* mb, int fr, int fg){
  bf16x8 bf[8]; loadB_lds(Bk,bf,fr,fg);
  float rc[4];
  if constexpr(MODE==1){
    #pragma unroll
    for(int n=0;n<4;n++) rc[n]=ra[n*16+fr].x;
  }
  #pragma unroll
  for(int rt=0;rt<4;rt++){
    const bf16x8 a0=fragld(Aq,16*rt+fr,fg*16), a1=fragld(Aq,16*rt+fr,64+fg*16);
    f32x4 acc[4]={{0,0,0,0},{0,0,0,0},{0,0,0,0},{0,0,0,0}};
    #pragma unroll
    for(int n=0;n<4;n++){
      acc[n]=MFMA16(a0,bf[2*n],acc[n]);
      acc[n]=MFMA16(a1,bf[2*n+1],acc[n]);
    }
    unsigned mbits=0;
    if constexpr(MODE==1){
      float aR[4],ucR[4],qtR[4]; bool gi[4];
      #pragma unroll
      for(int r=0;r<4;r++){
        const int R=16*rt+4*fg+r;
        const float2 rv=ra[R];
        gi[r]=rv.x>rv.y; aR[r]=rv.y;
        const float4 z4=zz[R];
        ucR[r]=z4.x+cu; qtR[r]=z4.y+cq;
      }
      #pragma unroll
      for(int n=0;n<4;n++){
        #pragma unroll
        for(int r=0;r<4;r++){
          const bool mv=gi[r]||(rc[n]>aR[r]);
          if(mv) mbits|=1u<<(n*4+r);
          const float mf=mv?1.f:0.f;
          acc[n][r]=(mf*(acc[n][r]+ucR[r])+qtR[r])*SCALE;
        }
      }
      mb[rt]=mbits;
    } else if constexpr(MODE==2){
      mbits = mb[rt]^0xffffu;
      float ucR[4],qtR[4];
      #pragma unroll
      for(int r=0;r<4;r++){
        const float4 z4=zz[16*rt+4*fg+r];
        ucR[r]=z4.z+cu; qtR[r]=z4.w+cq;
      }
      #pragma unroll
      for(int n=0;n<4;n++){
        #pragma unroll
        for(int r=0;r<4;r++){
          const float mf=((mbits>>(n*4+r))&1u)?1.f:0.f;
          acc[n][r]=(mf*(acc[n][r]+ucR[r])+qtR[r])*SCALE;
        }
      }
    }
    float mx[4];
    #pragma unroll
    for(int r=0;r<4;r++)
      mx[r]=fmaxf(fmaxf(acc[0][r],acc[1][r]),fmaxf(acc[2][r],acc[3][r]));
    #pragma unroll
    for(int m=1;m<16;m<<=1){
      #pragma unroll
      for(int r=0;r<4;r++) mx[r]=fmaxf(mx[r],__shfl_xor(mx[r],m));
    }
    float sm[4]={0,0,0,0}, smM[4]={0,0,0,0};
    #pragma unroll
    for(int n=0;n<4;n++){
      #pragma unroll
      for(int r=0;r<4;r++){
        float e;
        if constexpr(MODE==0) e=__expf((acc[n][r]-mx[r])*SCALE);
        else e=__expf(acc[n][r]-mx[r]);
        acc[n][r]=e; sm[r]+=e;
        if constexpr(MODE!=0){ if(mbits&(1u<<(n*4+r))) smM[r]+=e; }
      }
    }
    #pragma unroll
    for(int m=1;m<16;m<<=1){
      #pragma unroll
      for(int r=0;r<4;r++){
        sm[r]+=__shfl_xor(sm[r],m);
        if constexpr(MODE!=0) smM[r]+=__shfl_xor(smM[r],m);
      }
    }
    #pragma unroll
    for(int r=0;r<4;r++){
      const int R=16*rt+4*fg+r;
      const float ri=1.f/sm[r];
      if constexpr(MODE!=0) srout[rt][r]=smM[r]*ri;
      float v[4];
      #pragma unroll
      for(int n=0;n<4;n++){
        float e=acc[n][r]*ri;
        if constexpr(MODE!=0) e=(mbits&(1u<<(n*4+r)))?e:0.f;
        v[n]=e;
      }
      uint2 pk; pk.x=pack2(v[0],v[1]); pk.y=pack2(v[2],v[3]);
      *reinterpret_cast<uint2*>(P + R*128 + ((8*fr)^((R&7)<<4))) = pk;
    }
  }
}

// head phase: Dh[n] += HW(16x64 global, rows=out-dims) @ O(lds)^T
__device__ __forceinline__ void hstage(const char* HWp, const char* O, f32x4* Dh,
                                       int fr, int fg){
  const bf16x8 h0=gld(HWp + fr*256 + fg*16);
  const bf16x8 h1=gld(HWp + fr*256 + 64 + fg*16);
  #pragma unroll
  for(int n=0;n<4;n++){
    Dh[n]=MFMA16(h0, fragld(O,n*16+fr,fg*16),    Dh[n]);
    Dh[n]=MFMA16(h1, fragld(O,n*16+fr,64+fg*16), Dh[n]);
  }
}

__global__ __launch_bounds__(128,2) void rap_kernel(Params p, int Bb){
  __shared__ __align__(16) char T[ITEMS][3][8192];
  __shared__ __align__(16) float2 ra_s[ITEMS][64];
  __shared__ __align__(16) float4 zz_s[ITEMS][64];
  const int t=threadIdx.x, item=t>>6, l=t&63, fr=l&15, fg=l>>4;
  const int bidx=blockIdx.x*ITEMS+item;
  const int bi=(bidx<Bb)?bidx:(Bb-1);
  char* X=T[item][0]; char* Y=T[item][1]; char* Z=T[item][2];
  const float2* ra=ra_s[item];
  const float4* zz=zz_s[item];
  const char* ws=p.ws;
  const float* VECF=(const float*)(ws+WS_VEC);
  const float4 scf=*(const float4*)(ws+WS_SC);   // c1, hbk1, c2, hbk2

  // --- rnd + agent-rnd staging (wave-private) ---
  {
    const float r0=p.rnd[bi*64+l];
    const int   iv=p.idx[bi*64+l];
    const float av=p.rnd[bi*64+iv];
    ra_s[item][l]=make_float2(r0,av);
  }
  // --- x staging -> X (pi-packed cols + XOR rows), b128 LDS writes ---
  {
    const float* Gx=p.x+(size_t)bi*4096;
    #pragma unroll
    for(int w=0;w<8;w++){
      const int flat=w*64+l, R=flat>>3, k=flat&7;
      const float2 L0=*reinterpret_cast<const float2*>(Gx+R*64+2*k);
      const float2 L1=*reinterpret_cast<const float2*>(Gx+R*64+16+2*k);
      const float2 L2=*reinterpret_cast<const float2*>(Gx+R*64+32+2*k);
      const float2 L3=*reinterpret_cast<const float2*>(Gx+R*64+48+2*k);
      uint4 pk;
      pk.x=pack2(L0.x,L1.x); pk.y=pack2(L2.x,L3.x);
      pk.z=pack2(L0.y,L1.y); pk.w=pack2(L2.y,L3.y);
      *reinterpret_cast<uint4*>(X + R*128 + ((16*k)^((R&7)<<4)))=pk;
    }
  }
  bf16x8 bfv[8];
  float bz[4];
  // S1: E = lrelu(x@embed^T + eb) -> Y
  loadB_gl(ws+0*8192,bfv,fr,fg);
  #pragma unroll
  for(int n=0;n<4;n++) bz[n]=p.embed_b[n*16+fr];
  stage_mm<1,false,false>(X,bfv,Y,bz,nullptr,nullptr,fr,fg);
  // S2: T0' = E@M0 + m0 -> X
  loadB_gl(ws+1*8192,bfv,fr,fg);
  #pragma unroll
  for(int n=0;n<4;n++) bz[n]=VECF[n*16+fr];
  stage_mm<0,false,false>(Y,bfv,X,bz,nullptr,nullptr,fr,fg);
  // S3: P = softmax(T0'@E^T * SCALE) in-place X
  ssoft_f<0>(X,Y,X,nullptr,nullptr,0.f,0.f,nullptr,nullptr,fr,fg);
  // S4: VOT = Wvo@E^T -> Z (A from global)
  {
    const float bz0[4]={0,0,0,0};
    loadB_lds(Y,bfv,fr,fg);
    stage_mm<0,true,false>(ws+2*8192,bfv,Z,bz0,nullptr,nullptr,fr,fg);
  }
  // S5: ATT = tanh(P@VOT^T + cc) -> Y (normal) AND Z (transposed; VOT frags
  //     fully preloaded before Z is overwritten)
  {
    loadB_lds(Z,bfv,fr,fg);
    float cc[4];
    #pragma unroll
    for(int n=0;n<4;n++) cc[n]=VECF[64+n*16+fr];
    #pragma unroll
    for(int rt=0;rt<4;rt++){
      const bf16x8 a0=fragld(X,16*rt+fr,fg*16), a1=fragld(X,16*rt+fr,64+fg*16);
      f32x4 acc[4]={{0,0,0,0},{0,0,0,0},{0,0,0,0},{0,0,0,0}};
      #pragma unroll
      for(int n=0;n<4;n++){
        acc[n]=MFMA16(a0,bfv[2*n],acc[n]);
        acc[n]=MFMA16(a1,bfv[2*n+1],acc[n]);
      }
      float v[4][4];
      #pragma unroll
      for(int n=0;n<4;n++)
        #pragma unroll
        for(int r=0;r<4;r++) v[n][r]=actf<2>(acc[n][r]+cc[n]);
      #pragma unroll
      for(int r=0;r<4;r++){
        const int R=16*rt+4*fg+r;
        uint2 pk; pk.x=pack2(v[0][r],v[1][r]); pk.y=pack2(v[2][r],v[3][r]);
        *reinterpret_cast<uint2*>(Y + R*128 + ((8*fr)^((R&7)<<4)))=pk;
      }
      // transposed store: value (R, c=n*16+fr) -> Z[c][PI(R)], PI(R)=16fg+4r+rt
      #pragma unroll
      for(int n=0;n<4;n++){
        const int c=n*16+fr;
        #pragma unroll
        for(int r=0;r<4;r++){
          const int byte=c*128 + ((32*fg+8*r+2*rt) ^ ((fr&7)<<4));
          *reinterpret_cast<unsigned short*>(Z+byte)=f2b(v[n][r]);
        }
      }
    }
  }
  // S6: T1' = ATT@M1 + wt1 -> X ; Z-vec = ATT@Nv -> zz
  {
    loadB_gl(ws+3*8192,bfv,fr,fg);
    const bf16x8 nv0=gld(ws+WS_NV+fr*128+fg*16);
    const bf16x8 nv1=gld(ws+WS_NV+fr*128+64+fg*16);
    #pragma unroll
    for(int n=0;n<4;n++) bz[n]=VECF[128+n*16+fr];
    #pragma unroll
    for(int rt=0;rt<4;rt++){
      const bf16x8 a0=fragld(Y,16*rt+fr,fg*16), a1=fragld(Y,16*rt+fr,64+fg*16);
      f32x4 acc[4]={{0,0,0,0},{0,0,0,0},{0,0,0,0},{0,0,0,0}};
      #pragma unroll
      for(int n=0;n<4;n++){
        acc[n]=MFMA16(a0,bfv[2*n],acc[n]);
        acc[n]=MFMA16(a1,bfv[2*n+1],acc[n]);
      }
      f32x4 za={0,0,0,0};
      za=MFMA16(a0,nv0,za); za=MFMA16(a1,nv1,za);
      if(fr<4){
        #pragma unroll
        for(int r=0;r<4;r++)
          reinterpret_cast<float*>(&zz_s[item][16*rt+4*fg+r])[fr]=za[r];
      }
      #pragma unroll
      for(int r=0;r<4;r++){
        const int R=16*rt+4*fg+r;
        float v[4];
        #pragma unroll
        for(int n=0;n<4;n++) v[n]=acc[n][r]+bz[n];
        uint2 pk; pk.x=pack2(v[0],v[1]); pk.y=pack2(v[2],v[3]);
        *reinterpret_cast<uint2*>(X + R*128 + ((8*fr)^((R&7)<<4)))=pk;
      }
    }
  }
  unsigned mb[4];
  f32x4 sr1[4], sr2[4];
  // S7: P1 = cons-softmax(T1'@ATT^T), mask mg -> X (emits mb, sr1)
  ssoft_f<1>(X,Y,X,ra,zz,scf.x,scf.y,sr1,mb,fr,fg);
  // S8: R1 = P1@ATT -> X (Bt = ATTt in Z)
  {
    const float bz0[4]={0,0,0,0};
    loadB_lds(Z,bfv,fr,fg);
    stage_mm<0,false,false>(X,bfv,X,bz0,nullptr,nullptr,fr,fg);
  }
  // S9: O1 = lrelu(R1@Nw1^T + sr1*d1 + e1) -> X
  {
    loadB_gl(ws+4*8192,bfv,fr,fg);
    float dd[4];
    #pragma unroll
    for(int n=0;n<4;n++){ bz[n]=VECF[320+n*16+fr]; dd[n]=VECF[256+n*16+fr]; }
    stage_mm<1,false,true>(X,bfv,X,bz,sr1,dd,fr,fg);
  }
  // S10: heads phase 1: Dh += HWa @ O1^T
  f32x4 Dh[4]={{0,0,0,0},{0,0,0,0},{0,0,0,0},{0,0,0,0}};
  hstage(ws+WS_HW, X, Dh, fr, fg);
  // S11: T2' = ATT@M2 + wt2 -> X (O1 dead)
  loadB_gl(ws+5*8192,bfv,fr,fg);
  #pragma unroll
  for(int n=0;n<4;n++) bz[n]=VECF[192+n*16+fr];
  stage_mm<0,false,false>(Y,bfv,X,bz,nullptr,nullptr,fr,fg);
  // S12: P2 = cons-softmax(T2'@ATT^T), mask = ~mg -> X (sr2)
  ssoft_f<2>(X,Y,X,ra,zz,scf.z,scf.w,sr2,mb,fr,fg);
  // S13: R2 = P2@ATT -> X
  {
    const float bz0[4]={0,0,0,0};
    loadB_lds(Z,bfv,fr,fg);
    stage_mm<0,false,false>(X,bfv,X,bz0,nullptr,nullptr,fr,fg);
  }
  // S14: O2 = lrelu(R2@Nw2^T + sr2*d2 + e2) -> X
  {
    loadB_gl(ws+6*8192,bfv,fr,fg);
    float dd[4];
    #pragma unroll
    for(int n=0;n<4;n++){ bz[n]=VECF[448+n*16+fr]; dd[n]=VECF[384+n*16+fr]; }
    stage_mm<1,false,true>(X,bfv,X,bz,sr2,dd,fr,fg);
  }
  // S15: heads phase 2: Dh += HWb @ O2^T
  hstage(ws+WS_HW+128, X, Dh, fr, fg);
  // S16: write out: Dh[n][r] = D[od=4fg+r][agent=n*16+fr]
  if(bidx<Bb){
    float bzo[4];
    #pragma unroll
    for(int r=0;r<4;r++){
      const int od=4*fg+r;
      bzo[r]=(od<8)?p.mean_b[od]:p.ls_b[od-8];
    }
    #pragma unroll
    for(int n=0;n<4;n++){
      const int agent=n*16+fr;
      const long base=((long)bidx*64+agent)*8;
      #pragma unroll
      for(int r=0;r<4;r++){
        const int od=4*fg+r;
        float v=Dh[n][r]+bzo[r];
        if(od<8) p.out[base+od]=v;
        else{
          v=fminf(fmaxf(v,-20.f),2.f);
          p.out[p.std_off+base+od-8]=__expf(v);
        }
      }
    }
  }
}

} // namespace

extern "C" void kernel_launch(void* const* d_in, const int* in_sizes, int n_in,
                              void* d_out, int out_size, void* d_ws, size_t ws_size,
                              hipStream_t stream){
  (void)n_in; (void)out_size; (void)ws_size;
  PrepP q;
  q.embed_w=(const float*)d_in[3];
  q.ia_wq=(const float*)d_in[5];  q.ia_bq=(const float*)d_in[6];
  q.ia_wk=(const float*)d_in[7];
  q.ia_wv=(const float*)d_in[9];  q.ia_bv=(const float*)d_in[10];
  q.ia_wo=(const float*)d_in[11]; q.ia_bo=(const float*)d_in[12];
  q.c1_wq=(const float*)d_in[13]; q.c1_bq=(const float*)d_in[14];
  q.c1_wk=(const float*)d_in[15]; q.c1_bk=(const float*)d_in[16];
  q.c1_wv=(const float*)d_in[17]; q.c1_bv=(const float*)d_in[18];
  q.c1_wo=(const float*)d_in[19]; q.c1_bo=(const float*)d_in[20];
  q.c2_wq=(const float*)d_in[21]; q.c2_bq=(const float*)d_in[22];
  q.c2_wk=(const float*)d_in[23]; q.c2_bk=(const float*)d_in[24];
  q.c2_wv=(const float*)d_in[25]; q.c2_bv=(const float*)d_in[26];
  q.c2_wo=(const float*)d_in[27]; q.c2_bo=(const float*)d_in[28];
  q.msg_w=(const float*)d_in[29]; q.msg_b=(const float*)d_in[30];
  q.st_w =(const float*)d_in[31]; q.st_b =(const float*)d_in[32];
  q.mean_w=(const float*)d_in[33]; q.ls_w=(const float*)d_in[35];
  q.ws=(char*)d_ws;
  prep_kernel<<<dim3(7), dim3(256), 0, stream>>>(q);

  Params p;
  p.x  =(const float*)d_in[0];
  p.rnd=(const float*)d_in[1];
  p.idx=(const int*)  d_in[2];
  p.embed_b=(const float*)d_in[4];
  p.mean_b =(const float*)d_in[34];
  p.ls_b   =(const float*)d_in[36];
  p.ws=(const char*)d_ws;
  p.out=(float*)d_out;
  const int Bb=in_sizes[0]/4096;   // x is [B,64,64]
  p.std_off=Bb*64*8;
  const int nb=(Bb+ITEMS-1)/ITEMS;
  rap_kernel<<<dim3(nb), dim3(128), 0, stream>>>(p, Bb);
}

// Round 8
// 164.057 us; speedup vs baseline: 1.0497x; 1.0497x over previous
//
#include <hip/hip_runtime.h>

namespace {

typedef __bf16 bf16x8 __attribute__((ext_vector_type(8)));
typedef float f32x4 __attribute__((ext_vector_type(4)));
typedef unsigned int uint4v __attribute__((ext_vector_type(4)));

#define MFMA16(a,b,c) __builtin_amdgcn_mfma_f32_16x16x32_bf16((a),(b),(c),0,0,0)

constexpr float SCALE = 0.125f;   // 1/sqrt(64)

// ---------------- ws layout (all bf16 tiles COLUMN-pi-packed, plain row-major;
// read directly from global as MFMA fragments) ----------------
// slots i*8192, i=0..6: 0 embed, 1 M0T, 2 Wvo, 3 M1T, 4 Nw1, 5 M2T, 6 Nw2
constexpr int WS_HW  = 57344;  // head weights [16][128] bf16 (pi per 64-half), 4096 B
constexpr int WS_NV  = 61440;  // Nv tile [16][64] bf16 (rows 0-3 used), 2048 B
constexpr int WS_VEC = 63488;  // f32 vecs: m0,cc,wt1,wt2,d1,e1,d2,e2 (8 x 64)
constexpr int WS_SC  = 65536;  // f32 scalars: c1, hbk1, c2, hbk2

__device__ __forceinline__ int PI(int c){ return 4*(c&15) + (c>>4); }
__device__ __forceinline__ int PINV(int p){ return 16*(p&3) + (p>>2); }

__device__ __forceinline__ unsigned short f2b(float f){
  return __builtin_bit_cast(unsigned short, (__bf16)f);
}
__device__ __forceinline__ unsigned pack2(float a, float b){
  return (unsigned)f2b(a) | ((unsigned)f2b(b)<<16);
}
template<int ACT>  // 0 none, 1 leaky-relu(0.2), 2 tanh
__device__ __forceinline__ float actf(float v){
  if constexpr (ACT==1) return v>0.f ? v : 0.2f*v;
  else if constexpr (ACT==2) return 1.f - 2.f/(__expf(2.f*v)+1.f);
  else return v;
}

// ---------------- prep kernel (round-4/7 version, proven) ----------------
struct PrepP {
  const float *embed_w, *mean_w, *ls_w;
  const float *ia_wq, *ia_bq, *ia_wk, *ia_wv, *ia_wo, *ia_bv, *ia_bo;
  const float *c1_wq, *c1_bq, *c1_wk, *c1_bk, *c1_wv, *c1_bv, *c1_wo, *c1_bo;
  const float *c2_wq, *c2_bq, *c2_wk, *c2_bk, *c2_wv, *c2_bv, *c2_wo, *c2_bo;
  const float *msg_w, *msg_b, *st_w, *st_b;
  char* ws;
};

__device__ void mmAB_f32(const float* A, const float* B, float* O){
  const int t=threadIdx.x, r=t>>2, c0=(t&3)*16;
  float acc[16];
  #pragma unroll
  for(int j=0;j<16;j++) acc[j]=0.f;
  for(int h=0;h<64;h++){
    const float a=A[r*64+h];
    #pragma unroll
    for(int j=0;j<16;j++) acc[j]=fmaf(a,B[h*64+c0+j],acc[j]);
  }
  #pragma unroll
  for(int j=0;j<16;j++) O[r*64+c0+j]=acc[j];
}
__device__ void mmAB_bf(const float* A, const float* B, __bf16* D){
  const int t=threadIdx.x, r=t>>2, c0=(t&3)*16;
  float acc[16];
  #pragma unroll
  for(int j=0;j<16;j++) acc[j]=0.f;
  for(int h=0;h<64;h++){
    const float a=A[r*64+h];
    #pragma unroll
    for(int j=0;j<16;j++) acc[j]=fmaf(a,B[h*64+c0+j],acc[j]);
  }
  #pragma unroll
  for(int j=0;j<16;j++) D[r*64+PI(c0+j)]=(__bf16)acc[j];
}
__device__ void mmTA_bf(const float* A, const float* B, __bf16* D){
  const int t=threadIdx.x, a=t>>2, b0=(t&3)*16;
  float acc[16];
  #pragma unroll
  for(int j=0;j<16;j++) acc[j]=0.f;
  for(int h=0;h<64;h++){
    const float av=A[h*64+a];
    #pragma unroll
    for(int j=0;j<16;j++) acc[j]=fmaf(av,B[h*64+b0+j],acc[j]);
  }
  #pragma unroll
  for(int j=0;j<16;j++) D[a*64+PI(b0+j)]=(__bf16)acc[j];
}

__global__ void prep_kernel(PrepP q){
  __shared__ float PF[2][4096];
  __shared__ float hv[64], gv[64];
  const int job=blockIdx.x, t=threadIdx.x;
  char* ws=q.ws;
  float* VECF=(float*)(ws+WS_VEC);
  float* SCF =(float*)(ws+WS_SC);
  __bf16* NVD=(__bf16*)(ws+WS_NV);

  if(job==0){
    __bf16* emb=(__bf16*)(ws+0*8192);
    #pragma unroll
    for(int i=0;i<16;i++){
      const int idx=t*16+i, o=idx>>6, p=idx&63;
      emb[idx]=(__bf16)q.embed_w[o*64+PINV(p)];
    }
    __bf16* hw=(__bf16*)(ws+WS_HW);
    #pragma unroll
    for(int i=0;i<8;i++){
      const int flat=t*8+i, o=flat>>7, qq=flat&127, half=qq>>6, p=qq&63;
      const float v=(o<8)?q.mean_w[o*128+half*64+PINV(p)]
                         :q.ls_w[(o-8)*128+half*64+PINV(p)];
      hw[flat]=(__bf16)v;
    }
    #pragma unroll
    for(int i=0;i<3;i++){ const int id=t*3+i; if(id<768) NVD[256+id]=(__bf16)0.f; }
  } else if(job==1){
    mmTA_bf(q.ia_wk, q.ia_wq, (__bf16*)(ws+1*8192));
    if(t<64){ float s=0; for(int h=0;h<64;h++) s+=q.ia_wk[h*64+t]*q.ia_bq[h]; VECF[t]=s; }
  } else if(job==2){
    mmAB_bf(q.ia_wo, q.ia_wv, (__bf16*)(ws+2*8192));
    if(t<64){ float s=q.ia_bo[t]; for(int h=0;h<64;h++) s+=q.ia_wo[t*64+h]*q.ia_bv[h];
              VECF[64+t]=s; }
  } else if(job==3 || job==5){
    const int cons=(job==3)?0:1;
    const float *wq=cons?q.c2_wq:q.c1_wq, *bq=cons?q.c2_bq:q.c1_bq;
    const float *wk=cons?q.c2_wk:q.c1_wk, *bk=cons?q.c2_bk:q.c1_bk;
    mmAB_f32(wq, q.st_w, PF[0]);                       // G = wq@st_w
    if(t<64){ float s=bq[t]; for(int k=0;k<64;k++) s+=wq[t*64+k]*q.st_b[k]; hv[t]=s; }
    __syncthreads();
    mmAB_f32(wk, q.msg_w, PF[1]);                      // F = wk@msg_w
    if(t<64){ float s=0; for(int k=0;k<64;k++) s+=wk[t*64+k]*q.msg_b[k]; gv[t]=s; }
    __syncthreads();
    mmTA_bf(PF[1], PF[0], (__bf16*)(ws+(cons?5:3)*8192));  // M1T/M2T
    if(t<64){
      float s=0; for(int h=0;h<64;h++) s+=PF[1][h*64+t]*hv[h];
      VECF[128+cons*64+t]=s;                            // wt = F^T h
      float s0=0,s1=0;
      for(int h=0;h<64;h++){ s0+=PF[0][h*64+t]*gv[h]; s1+=PF[0][h*64+t]*bk[h]; }
      NVD[(2*cons  )*64+PI(t)]=(__bf16)s0;              // u-vec  = G^T g
      NVD[(2*cons+1)*64+PI(t)]=(__bf16)s1;              // qb-vec = G^T bk
    }
    if(t==0){
      float c=0,hb=0;
      for(int i=0;i<64;i++){ c+=hv[i]*gv[i]; hb+=hv[i]*bk[i]; }
      SCF[2*cons]=c; SCF[2*cons+1]=hb;
    }
  } else {
    const int cons=(job==4)?0:1;
    const float *wo=cons?q.c2_wo:q.c1_wo, *wvv=cons?q.c2_wv:q.c1_wv;
    const float *bv=cons?q.c2_bv:q.c1_bv, *bo=cons?q.c2_bo:q.c1_bo;
    mmAB_f32(wo, wvv, PF[0]);                          // U = wo@wv
    if(t<64){ float s=bo[t]; for(int h=0;h<64;h++) s+=wo[t*64+h]*bv[h];
              VECF[320+cons*128+t]=s; }                 // e = wo@bv + bo
    __syncthreads();
    mmAB_bf(PF[0], q.msg_w, (__bf16*)(ws+(cons?6:4)*8192));  // Nw
    if(t<64){ float s=0; for(int k=0;k<64;k++) s+=PF[0][t*64+k]*q.msg_b[k];
              VECF[256+cons*128+t]=s; }                 // d = U@msg_b
  }
}

// ---------------- main kernel: 1 item / 256-thr block, 4 waves, 6 barriers ----
struct Params {
  const float *x, *rnd; const int *idx;
  const float *embed_b, *mean_b, *ls_b;
  const char* ws; float* out; int std_off;
};

// LDS tile fragment read (XOR-swizzled rows, 16B, conflict-free)
__device__ __forceinline__ bf16x8 fragld(const char* buf, int row, int kb){
  const int byte = row*128 + (kb ^ ((row&7)<<4));
  return __builtin_bit_cast(bf16x8, *reinterpret_cast<const uint4v*>(buf + byte));
}
__device__ __forceinline__ bf16x8 gld(const char* a){
  return __builtin_bit_cast(bf16x8, *reinterpret_cast<const uint4v*>(a));
}
__device__ __forceinline__ void loadB_lds(const char* Bl, bf16x8* bf, int fr, int fg){
  #pragma unroll
  for(int n=0;n<4;n++){
    bf[2*n]   = fragld(Bl, n*16+fr, fg*16);
    bf[2*n+1] = fragld(Bl, n*16+fr, 64+fg*16);
  }
}
__device__ __forceinline__ void loadB_gl(const char* W, bf16x8* bf, int fr, int fg){
  #pragma unroll
  for(int n=0;n<4;n++){
    bf[2*n]   = gld(W + (n*16+fr)*128 + fg*16);
    bf[2*n+1] = gld(W + (n*16+fr)*128 + 64 + fg*16);
  }
}

// acc = A(own 16 rows) @ bf^T ; A from LDS (AG=0, XOR) or global (AG=1, plain)
template<bool AG>
__device__ __forceinline__ void mm_acc(const char* A, const bf16x8* bf, f32x4* acc,
                                       int fr, int fg, int wv4){
  bf16x8 a0,a1;
  if constexpr(AG){
    a0=gld(A+(16*wv4+fr)*128+fg*16); a1=gld(A+(16*wv4+fr)*128+64+fg*16);
  } else {
    a0=fragld(A,16*wv4+fr,fg*16); a1=fragld(A,16*wv4+fr,64+fg*16);
  }
  #pragma unroll
  for(int n=0;n<4;n++){
    acc[n]=MFMA16(a0,bf[2*n],acc[n]);
    acc[n]=MFMA16(a1,bf[2*n+1],acc[n]);
  }
}
// store own rows: C = ACT(acc + bz[col]); pi-packed cols, XOR rows, b64
template<int ACT>
__device__ __forceinline__ void st_cb(char* C, const f32x4* acc, const float* bz,
                                      int fr, int fg, int wv4){
  #pragma unroll
  for(int r=0;r<4;r++){
    const int R=16*wv4+4*fg+r;
    float v[4];
    #pragma unroll
    for(int n=0;n<4;n++) v[n]=actf<ACT>(acc[n][r]+bz[n]);
    uint2 pk; pk.x=pack2(v[0],v[1]); pk.y=pack2(v[2],v[3]);
    *reinterpret_cast<uint2*>(C + R*128 + ((8*fr)^((R&7)<<4))) = pk;
  }
}
// store own rows with per-ROW bias (d-fold), no activation
__device__ __forceinline__ void st_rb(char* C, const f32x4* acc, const float* dbase,
                                      int fr, int fg, int wv4){
  #pragma unroll
  for(int r=0;r<4;r++){
    const int R=16*wv4+4*fg+r;
    const float d=dbase[R];
    float v[4];
    #pragma unroll
    for(int n=0;n<4;n++) v[n]=acc[n][r]+d;
    uint2 pk; pk.x=pack2(v[0],v[1]); pk.y=pack2(v[2],v[3]);
    *reinterpret_cast<uint2*>(C + R*128 + ((8*fr)^((R&7)<<4))) = pk;
  }
}

// MODE 0: P=softmax(S*SCALE). MODE 1: consensus mg (emits mbio). MODE 2: ~mbio.
template<int MODE>
__device__ __forceinline__ void ssoft(const char* Aq, const char* Bk, char* P,
                                      const float2* ra, const float4* zz,
                                      float cu, float cq, unsigned& mbio,
                                      int fr, int fg, int wv4){
  bf16x8 bf[8]; loadB_lds(Bk,bf,fr,fg);
  f32x4 acc[4]={{0,0,0,0},{0,0,0,0},{0,0,0,0},{0,0,0,0}};
  mm_acc<false>(Aq,bf,acc,fr,fg,wv4);
  unsigned mbits=0;
  if constexpr(MODE==1){
    float rc[4],aR[4],ucR[4],qtR[4]; bool gi[4];
    #pragma unroll
    for(int n=0;n<4;n++) rc[n]=ra[n*16+fr].x;
    #pragma unroll
    for(int r=0;r<4;r++){
      const int R=16*wv4+4*fg+r;
      const float2 rv=ra[R];
      gi[r]=rv.x>rv.y; aR[r]=rv.y;
      const float4 z4=zz[R];
      ucR[r]=z4.x+cu; qtR[r]=z4.y+cq;
    }
    #pragma unroll
    for(int n=0;n<4;n++){
      #pragma unroll
      for(int r=0;r<4;r++){
        const bool mv=gi[r]||(rc[n]>aR[r]);
        if(mv) mbits|=1u<<(n*4+r);
        const float mf=mv?1.f:0.f;
        acc[n][r]=(mf*(acc[n][r]+ucR[r])+qtR[r])*SCALE;
      }
    }
    mbio=mbits;
  } else if constexpr(MODE==2){
    mbits=mbio^0xffffu;
    float ucR[4],qtR[4];
    #pragma unroll
    for(int r=0;r<4;r++){
      const float4 z4=zz[16*wv4+4*fg+r];
      ucR[r]=z4.z+cu; qtR[r]=z4.w+cq;
    }
    #pragma unroll
    for(int n=0;n<4;n++){
      #pragma unroll
      for(int r=0;r<4;r++){
        const float mf=((mbits>>(n*4+r))&1u)?1.f:0.f;
        acc[n][r]=(mf*(acc[n][r]+ucR[r])+qtR[r])*SCALE;
      }
    }
  }
  float mx[4];
  #pragma unroll
  for(int r=0;r<4;r++)
    mx[r]=fmaxf(fmaxf(acc[0][r],acc[1][r]),fmaxf(acc[2][r],acc[3][r]));
  #pragma unroll
  for(int m=1;m<16;m<<=1){
    #pragma unroll
    for(int r=0;r<4;r++) mx[r]=fmaxf(mx[r],__shfl_xor(mx[r],m));
  }
  float sm[4]={0,0,0,0};
  #pragma unroll
  for(int n=0;n<4;n++){
    #pragma unroll
    for(int r=0;r<4;r++){
      float e;
      if constexpr(MODE==0) e=__expf((acc[n][r]-mx[r])*SCALE);
      else e=__expf(acc[n][r]-mx[r]);
      acc[n][r]=e; sm[r]+=e;
    }
  }
  #pragma unroll
  for(int m=1;m<16;m<<=1){
    #pragma unroll
    for(int r=0;r<4;r++) sm[r]+=__shfl_xor(sm[r],m);
  }
  #pragma unroll
  for(int r=0;r<4;r++){
    const int R=16*wv4+4*fg+r;
    const float ri=1.f/sm[r];
    float v[4];
    #pragma unroll
    for(int n=0;n<4;n++){
      float e=acc[n][r]*ri;
      if constexpr(MODE!=0) e=(mbits&(1u<<(n*4+r)))?e:0.f;
      v[n]=e;
    }
    uint2 pk; pk.x=pack2(v[0],v[1]); pk.y=pack2(v[2],v[3]);
    *reinterpret_cast<uint2*>(P + R*128 + ((8*fr)^((R&7)<<4))) = pk;
  }
}

// park O=lrelu(oacc+e) into Buf own rows, then fold into hacc via 2 head MFMAs
__device__ __forceinline__ void park_heads(char* Buf, const f32x4* oacc,
                                           const float* ev, const char* hwb,
                                           f32x4& hacc, int fr, int fg, int wv4){
  float bz[4];
  #pragma unroll
  for(int n=0;n<4;n++) bz[n]=ev[n*16+fr];
  st_cb<1>(Buf,oacc,bz,fr,fg,wv4);
  const bf16x8 af0=fragld(Buf,16*wv4+fr,fg*16);
  const bf16x8 af1=fragld(Buf,16*wv4+fr,64+fg*16);
  hacc=MFMA16(af0, gld(hwb+fr*256+fg*16),    hacc);
  hacc=MFMA16(af1, gld(hwb+fr*256+64+fg*16), hacc);
}

__global__ __launch_bounds__(256,6) void rap_kernel(Params p){
  __shared__ __align__(16) char X[8192];
  __shared__ __align__(16) char Y[8192];
  __shared__ __align__(16) char Z[8192];
  __shared__ __align__(16) float2 ra_s[64];
  __shared__ __align__(16) float4 zz_s[64];
  const int t=threadIdx.x, l=t&63, fr=l&15, fg=l>>4, wv4=t>>6;
  const int bi=blockIdx.x;
  const char* ws=p.ws;
  const float* VECF=(const float*)(ws+WS_VEC);
  const float4 scf=*(const float4*)(ws+WS_SC);   // c1, hbk1, c2, hbk2
  const float2* ra=ra_s;
  const float4* zz=zz_s;

  if(t<64){
    const float r0=p.rnd[bi*64+t];
    const float av=p.rnd[bi*64+p.idx[bi*64+t]];
    ra_s[t]=make_float2(r0,av);
  }
  // x staging: OWN 16 rows, pi+XOR, b128 stores (2 iters/thread)
  {
    const float* Gx=p.x+(size_t)bi*4096;
    #pragma unroll
    for(int j=0;j<2;j++){
      const int lf=j*64+l, R=16*wv4+(lf>>3), k=lf&7;
      const float2 L0=*reinterpret_cast<const float2*>(Gx+R*64+2*k);
      const float2 L1=*reinterpret_cast<const float2*>(Gx+R*64+16+2*k);
      const float2 L2=*reinterpret_cast<const float2*>(Gx+R*64+32+2*k);
      const float2 L3=*reinterpret_cast<const float2*>(Gx+R*64+48+2*k);
      uint4 pk;
      pk.x=pack2(L0.x,L1.x); pk.y=pack2(L2.x,L3.x);
      pk.z=pack2(L0.y,L1.y); pk.w=pack2(L2.y,L3.y);
      *reinterpret_cast<uint4*>(X + R*128 + ((16*k)^((R&7)<<4)))=pk;
    }
  }
  bf16x8 bfv[8];
  float bz[4];
  f32x4 acc[4];
  unsigned mb=0;
  // S1: E = lrelu(x@embed^T + eb) -> Y (own rows); B JIT
  loadB_gl(ws+0*8192,bfv,fr,fg);
  #pragma unroll
  for(int n=0;n<4;n++){ bz[n]=p.embed_b[n*16+fr]; acc[n]=f32x4{0,0,0,0}; }
  mm_acc<false>(X,bfv,acc,fr,fg,wv4);
  st_cb<1>(Y,acc,bz,fr,fg,wv4);
  // S2: T0' = E@M0 + m0 -> X (own rows)
  loadB_gl(ws+1*8192,bfv,fr,fg);
  #pragma unroll
  for(int n=0;n<4;n++){ bz[n]=VECF[n*16+fr]; acc[n]=f32x4{0,0,0,0}; }
  mm_acc<false>(Y,bfv,acc,fr,fg,wv4);
  st_cb<0>(X,acc,bz,fr,fg,wv4);
  __syncthreads();                                   // BAR1: E full
  // S3: P = softmax(T0'@E^T * SCALE) in-place X
  ssoft<0>(X,Y,X,nullptr,nullptr,0.f,0.f,mb,fr,fg,wv4);
  // S4: VOT = Wvo@E^T -> Z (A global own rows, B=Y full)
  loadB_lds(Y,bfv,fr,fg);
  #pragma unroll
  for(int n=0;n<4;n++){ bz[n]=0.f; acc[n]=f32x4{0,0,0,0}; }
  mm_acc<true>(ws+2*8192,bfv,acc,fr,fg,wv4);
  st_cb<0>(Z,acc,bz,fr,fg,wv4);
  __syncthreads();                                   // BAR2: VOT full (E dead)
  // S5: ATT = tanh(P@VOT^T + cc) -> Y (own rows)
  loadB_lds(Z,bfv,fr,fg);
  #pragma unroll
  for(int n=0;n<4;n++){ bz[n]=VECF[64+n*16+fr]; acc[n]=f32x4{0,0,0,0}; }
  mm_acc<false>(X,bfv,acc,fr,fg,wv4);
  st_cb<2>(Y,acc,bz,fr,fg,wv4);
  // S6: T1' = ATT@M1 + wt1 -> X ; zz = ATT@Nv (own rows; A=Y just written own)
  {
    loadB_gl(ws+3*8192,bfv,fr,fg);
    const bf16x8 nv0=gld(ws+WS_NV+fr*128+fg*16);
    const bf16x8 nv1=gld(ws+WS_NV+fr*128+64+fg*16);
    const bf16x8 a0=fragld(Y,16*wv4+fr,fg*16), a1=fragld(Y,16*wv4+fr,64+fg*16);
    #pragma unroll
    for(int n=0;n<4;n++){ bz[n]=VECF[128+n*16+fr]; acc[n]=f32x4{0,0,0,0}; }
    #pragma unroll
    for(int n=0;n<4;n++){
      acc[n]=MFMA16(a0,bfv[2*n],acc[n]);
      acc[n]=MFMA16(a1,bfv[2*n+1],acc[n]);
    }
    f32x4 za={0,0,0,0};
    za=MFMA16(a0,nv0,za); za=MFMA16(a1,nv1,za);
    if(fr<4){
      #pragma unroll
      for(int r=0;r<4;r++)
        reinterpret_cast<float*>(&zz_s[16*wv4+4*fg+r])[fr]=za[r];
    }
    st_cb<0>(X,acc,bz,fr,fg,wv4);
  }
  __syncthreads();                                   // BAR3: ATT + zz full
  // S7: P1 = cons-softmax(T1'@ATT^T) in-place X (emits mb)
  ssoft<1>(X,Y,X,ra,zz,scf.x,scf.y,mb,fr,fg,wv4);
  // S7b: VMO1T = Nw1@ATT^T + d1 -> Z (A global own rows, B=Y full)
  loadB_lds(Y,bfv,fr,fg);
  #pragma unroll
  for(int n=0;n<4;n++) acc[n]=f32x4{0,0,0,0};
  mm_acc<true>(ws+4*8192,bfv,acc,fr,fg,wv4);
  st_rb(Z,acc,VECF+256,fr,fg,wv4);
  __syncthreads();                                   // BAR4: VMO1T full
  f32x4 hacc={0,0,0,0};
  // S8: o1acc = P1@VMO1T^T ; park O1 -> X own rows; fold into hacc (HW cols 0-63)
  loadB_lds(Z,bfv,fr,fg);
  #pragma unroll
  for(int n=0;n<4;n++) acc[n]=f32x4{0,0,0,0};
  mm_acc<false>(X,bfv,acc,fr,fg,wv4);
  park_heads(X,acc,VECF+320,ws+WS_HW,hacc,fr,fg,wv4);
  // S9: T2' = ATT@M2 + wt2 -> X (own rows, over O1 — already consumed)
  loadB_gl(ws+5*8192,bfv,fr,fg);
  #pragma unroll
  for(int n=0;n<4;n++){ bz[n]=VECF[192+n*16+fr]; acc[n]=f32x4{0,0,0,0}; }
  mm_acc<false>(Y,bfv,acc,fr,fg,wv4);
  st_cb<0>(X,acc,bz,fr,fg,wv4);
  // S10: P2 = cons-softmax(T2'@ATT^T, ~mb) in-place X
  ssoft<2>(X,Y,X,ra,zz,scf.z,scf.w,mb,fr,fg,wv4);
  __syncthreads();                                   // BAR5: all S8 Z-reads done
  // S11: VMO2T = Nw2@ATT^T + d2 -> Z (A global own rows, B=Y full, last Y use)
  loadB_lds(Y,bfv,fr,fg);
  #pragma unroll
  for(int n=0;n<4;n++) acc[n]=f32x4{0,0,0,0};
  mm_acc<true>(ws+6*8192,bfv,acc,fr,fg,wv4);
  st_rb(Z,acc,VECF+384,fr,fg,wv4);
  __syncthreads();                                   // BAR6: VMO2T full, Y free
  // S12: o2acc = P2@VMO2T^T ; park O2 -> Y own rows; fold into hacc (HW cols 64-127)
  loadB_lds(Z,bfv,fr,fg);
  #pragma unroll
  for(int n=0;n<4;n++) acc[n]=f32x4{0,0,0,0};
  mm_acc<false>(X,bfv,acc,fr,fg,wv4);
  park_heads(Y,acc,VECF+448,ws+WS_HW+128,hacc,fr,fg,wv4);
  // out: row = agent (own), col fr = out-dim
  {
    const float bzo=(fr<8)?p.mean_b[fr]:p.ls_b[fr-8];
    #pragma unroll
    for(int r=0;r<4;r++){
      const int R=16*wv4+4*fg+r;
      const long base=((long)bi*64+R)*8;
      float v=hacc[r]+bzo;
      if(fr<8) p.out[base+fr]=v;
      else{
        v=fminf(fmaxf(v,-20.f),2.f);
        p.out[p.std_off+base+fr-8]=__expf(v);
      }
    }
  }
}

} // namespace

extern "C" void kernel_launch(void* const* d_in, const int* in_sizes, int n_in,
                              void* d_out, int out_size, void* d_ws, size_t ws_size,
                              hipStream_t stream){
  (void)n_in; (void)out_size; (void)ws_size;
  PrepP q;
  q.embed_w=(const float*)d_in[3];
  q.ia_wq=(const float*)d_in[5];  q.ia_bq=(const float*)d_in[6];
  q.ia_wk=(const float*)d_in[7];
  q.ia_wv=(const float*)d_in[9];  q.ia_bv=(const float*)d_in[10];
  q.ia_wo=(const float*)d_in[11]; q.ia_bo=(const float*)d_in[12];
  q.c1_wq=(const float*)d_in[13]; q.c1_bq=(const float*)d_in[14];
  q.c1_wk=(const float*)d_in[15]; q.c1_bk=(const float*)d_in[16];
  q.c1_wv=(const float*)d_in[17]; q.c1_bv=(const float*)d_in[18];
  q.c1_wo=(const float*)d_in[19]; q.c1_bo=(const float*)d_in[20];
  q.c2_wq=(const float*)d_in[21]; q.c2_bq=(const float*)d_in[22];
  q.c2_wk=(const float*)d_in[23]; q.c2_bk=(const float*)d_in[24];
  q.c2_wv=(const float*)d_in[25]; q.c2_bv=(const float*)d_in[26];
  q.c2_wo=(const float*)d_in[27]; q.c2_bo=(const float*)d_in[28];
  q.msg_w=(const float*)d_in[29]; q.msg_b=(const float*)d_in[30];
  q.st_w =(const float*)d_in[31]; q.st_b =(const float*)d_in[32];
  q.mean_w=(const float*)d_in[33]; q.ls_w=(const float*)d_in[35];
  q.ws=(char*)d_ws;
  prep_kernel<<<dim3(7), dim3(256), 0, stream>>>(q);

  Params p;
  p.x  =(const float*)d_in[0];
  p.rnd=(const float*)d_in[1];
  p.idx=(const int*)  d_in[2];
  p.embed_b=(const float*)d_in[4];
  p.mean_b =(const float*)d_in[34];
  p.ls_b   =(const float*)d_in[36];
  p.ws=(const char*)d_ws;
  p.out=(float*)d_out;
  const int Bb=in_sizes[0]/4096;   // x is [B,64,64]
  p.std_off=Bb*64*8;
  rap_kernel<<<dim3(Bb), dim3(256), 0, stream>>>(p);
}

// Round 9
// 126.749 us; speedup vs baseline: 1.3587x; 1.2943x over previous
//
#include <hip/hip_runtime.h>

namespace {

typedef __bf16 bf16x8 __attribute__((ext_vector_type(8)));
typedef float f32x4 __attribute__((ext_vector_type(4)));
typedef unsigned int uint4v __attribute__((ext_vector_type(4)));

#define MFMA16(a,b,c) __builtin_amdgcn_mfma_f32_16x16x32_bf16((a),(b),(c),0,0,0)

constexpr float SCALE = 0.125f;   // 1/sqrt(64)

// ---------------- ws layout (all bf16 tiles COLUMN-pi-packed, plain row-major;
// read directly from global as MFMA fragments) ----------------
// slots i*8192, i=0..6: 0 embed, 1 M0T, 2 Wvo, 3 M1T, 4 Nw1, 5 M2T, 6 Nw2
constexpr int WS_HW  = 57344;  // head weights [16][128] bf16 (pi per 64-half), 4096 B
constexpr int WS_NV  = 61440;  // Nv tile [16][64] bf16 (rows 0-3 used), 2048 B
constexpr int WS_VEC = 63488;  // f32 vecs: m0,cc,wt1,wt2,d1,e1,d2,e2 (8 x 64)
constexpr int WS_SC  = 65536;  // f32 scalars: c1, hbk1, c2, hbk2

__device__ __forceinline__ int PI(int c){ return 4*(c&15) + (c>>4); }
__device__ __forceinline__ int PINV(int p){ return 16*(p&3) + (p>>2); }

__device__ __forceinline__ unsigned short f2b(float f){
  return __builtin_bit_cast(unsigned short, (__bf16)f);
}
__device__ __forceinline__ unsigned pack2(float a, float b){
  return (unsigned)f2b(a) | ((unsigned)f2b(b)<<16);
}
template<int ACT>  // 0 none, 1 leaky-relu(0.2), 2 tanh
__device__ __forceinline__ float actf(float v){
  if constexpr (ACT==1) return v>0.f ? v : 0.2f*v;
  else if constexpr (ACT==2) return 1.f - 2.f/(__expf(2.f*v)+1.f);
  else return v;
}

// ---------------- prep kernel (proven, unchanged) ----------------
struct PrepP {
  const float *embed_w, *mean_w, *ls_w;
  const float *ia_wq, *ia_bq, *ia_wk, *ia_wv, *ia_wo, *ia_bv, *ia_bo;
  const float *c1_wq, *c1_bq, *c1_wk, *c1_bk, *c1_wv, *c1_bv, *c1_wo, *c1_bo;
  const float *c2_wq, *c2_bq, *c2_wk, *c2_bk, *c2_wv, *c2_bv, *c2_wo, *c2_bo;
  const float *msg_w, *msg_b, *st_w, *st_b;
  char* ws;
};

__device__ void mmAB_f32(const float* A, const float* B, float* O){
  const int t=threadIdx.x, r=t>>2, c0=(t&3)*16;
  float acc[16];
  #pragma unroll
  for(int j=0;j<16;j++) acc[j]=0.f;
  for(int h=0;h<64;h++){
    const float a=A[r*64+h];
    #pragma unroll
    for(int j=0;j<16;j++) acc[j]=fmaf(a,B[h*64+c0+j],acc[j]);
  }
  #pragma unroll
  for(int j=0;j<16;j++) O[r*64+c0+j]=acc[j];
}
__device__ void mmAB_bf(const float* A, const float* B, __bf16* D){
  const int t=threadIdx.x, r=t>>2, c0=(t&3)*16;
  float acc[16];
  #pragma unroll
  for(int j=0;j<16;j++) acc[j]=0.f;
  for(int h=0;h<64;h++){
    const float a=A[r*64+h];
    #pragma unroll
    for(int j=0;j<16;j++) acc[j]=fmaf(a,B[h*64+c0+j],acc[j]);
  }
  #pragma unroll
  for(int j=0;j<16;j++) D[r*64+PI(c0+j)]=(__bf16)acc[j];
}
__device__ void mmTA_bf(const float* A, const float* B, __bf16* D){
  const int t=threadIdx.x, a=t>>2, b0=(t&3)*16;
  float acc[16];
  #pragma unroll
  for(int j=0;j<16;j++) acc[j]=0.f;
  for(int h=0;h<64;h++){
    const float av=A[h*64+a];
    #pragma unroll
    for(int j=0;j<16;j++) acc[j]=fmaf(av,B[h*64+b0+j],acc[j]);
  }
  #pragma unroll
  for(int j=0;j<16;j++) D[a*64+PI(b0+j)]=(__bf16)acc[j];
}

__global__ void prep_kernel(PrepP q){
  __shared__ float PF[2][4096];
  __shared__ float hv[64], gv[64];
  const int job=blockIdx.x, t=threadIdx.x;
  char* ws=q.ws;
  float* VECF=(float*)(ws+WS_VEC);
  float* SCF =(float*)(ws+WS_SC);
  __bf16* NVD=(__bf16*)(ws+WS_NV);

  if(job==0){
    __bf16* emb=(__bf16*)(ws+0*8192);
    #pragma unroll
    for(int i=0;i<16;i++){
      const int idx=t*16+i, o=idx>>6, p=idx&63;
      emb[idx]=(__bf16)q.embed_w[o*64+PINV(p)];
    }
    __bf16* hw=(__bf16*)(ws+WS_HW);
    #pragma unroll
    for(int i=0;i<8;i++){
      const int flat=t*8+i, o=flat>>7, qq=flat&127, half=qq>>6, p=qq&63;
      const float v=(o<8)?q.mean_w[o*128+half*64+PINV(p)]
                         :q.ls_w[(o-8)*128+half*64+PINV(p)];
      hw[flat]=(__bf16)v;
    }
    #pragma unroll
    for(int i=0;i<3;i++){ const int id=t*3+i; if(id<768) NVD[256+id]=(__bf16)0.f; }
  } else if(job==1){
    mmTA_bf(q.ia_wk, q.ia_wq, (__bf16*)(ws+1*8192));
    if(t<64){ float s=0; for(int h=0;h<64;h++) s+=q.ia_wk[h*64+t]*q.ia_bq[h]; VECF[t]=s; }
  } else if(job==2){
    mmAB_bf(q.ia_wo, q.ia_wv, (__bf16*)(ws+2*8192));
    if(t<64){ float s=q.ia_bo[t]; for(int h=0;h<64;h++) s+=q.ia_wo[t*64+h]*q.ia_bv[h];
              VECF[64+t]=s; }
  } else if(job==3 || job==5){
    const int cons=(job==3)?0:1;
    const float *wq=cons?q.c2_wq:q.c1_wq, *bq=cons?q.c2_bq:q.c1_bq;
    const float *wk=cons?q.c2_wk:q.c1_wk, *bk=cons?q.c2_bk:q.c1_bk;
    mmAB_f32(wq, q.st_w, PF[0]);                       // G = wq@st_w
    if(t<64){ float s=bq[t]; for(int k=0;k<64;k++) s+=wq[t*64+k]*q.st_b[k]; hv[t]=s; }
    __syncthreads();
    mmAB_f32(wk, q.msg_w, PF[1]);                      // F = wk@msg_w
    if(t<64){ float s=0; for(int k=0;k<64;k++) s+=wk[t*64+k]*q.msg_b[k]; gv[t]=s; }
    __syncthreads();
    mmTA_bf(PF[1], PF[0], (__bf16*)(ws+(cons?5:3)*8192));  // M1T/M2T
    if(t<64){
      float s=0; for(int h=0;h<64;h++) s+=PF[1][h*64+t]*hv[h];
      VECF[128+cons*64+t]=s;                            // wt = F^T h
      float s0=0,s1=0;
      for(int h=0;h<64;h++){ s0+=PF[0][h*64+t]*gv[h]; s1+=PF[0][h*64+t]*bk[h]; }
      NVD[(2*cons  )*64+PI(t)]=(__bf16)s0;              // u-vec  = G^T g
      NVD[(2*cons+1)*64+PI(t)]=(__bf16)s1;              // qb-vec = G^T bk
    }
    if(t==0){
      float c=0,hb=0;
      for(int i=0;i<64;i++){ c+=hv[i]*gv[i]; hb+=hv[i]*bk[i]; }
      SCF[2*cons]=c; SCF[2*cons+1]=hb;
    }
  } else {
    const int cons=(job==4)?0:1;
    const float *wo=cons?q.c2_wo:q.c1_wo, *wvv=cons?q.c2_wv:q.c1_wv;
    const float *bv=cons?q.c2_bv:q.c1_bv, *bo=cons?q.c2_bo:q.c1_bo;
    mmAB_f32(wo, wvv, PF[0]);                          // U = wo@wv
    if(t<64){ float s=bo[t]; for(int h=0;h<64;h++) s+=wo[t*64+h]*bv[h];
              VECF[320+cons*128+t]=s; }                 // e = wo@bv + bo
    __syncthreads();
    mmAB_bf(PF[0], q.msg_w, (__bf16*)(ws+(cons?6:4)*8192));  // Nw
    if(t<64){ float s=0; for(int k=0;k<64;k++) s+=PF[0][t*64+k]*q.msg_b[k];
              VECF[256+cons*128+t]=s; }                 // d = U@msg_b
  }
}

// ---------------- main kernel: 1 item / 128-thr (2-wave) block ----------------
struct Params {
  const float *x, *rnd; const int *idx;
  const float *embed_b, *mean_b, *ls_b;
  const char* ws; float* out; int std_off;
};

__device__ __forceinline__ bf16x8 fragld(const char* buf, int row, int kb){
  const int byte = row*128 + (kb ^ ((row&7)<<4));
  return __builtin_bit_cast(bf16x8, *reinterpret_cast<const uint4v*>(buf + byte));
}
__device__ __forceinline__ bf16x8 gld(const char* a){
  return __builtin_bit_cast(bf16x8, *reinterpret_cast<const uint4v*>(a));
}
__device__ __forceinline__ void loadB_lds(const char* Bl, bf16x8* bf, int fr, int fg){
  #pragma unroll
  for(int n=0;n<4;n++){
    bf[2*n]   = fragld(Bl, n*16+fr, fg*16);
    bf[2*n+1] = fragld(Bl, n*16+fr, 64+fg*16);
  }
}
__device__ __forceinline__ void loadB_gl(const char* W, bf16x8* bf, int fr, int fg){
  #pragma unroll
  for(int n=0;n<4;n++){
    bf[2*n]   = gld(W + (n*16+fr)*128 + fg*16);
    bf[2*n+1] = gld(W + (n*16+fr)*128 + 64 + fg*16);
  }
}

// acc[rt][n] = A(rows row0+16rt..+16) @ bf^T ; A LDS (AG=0) or global (AG=1)
template<bool AG>
__device__ __forceinline__ void mm2(const char* A, const bf16x8* bf,
                                    f32x4 acc[2][4], int fr, int fg, int row0){
  #pragma unroll
  for(int rt=0;rt<2;rt++){
    bf16x8 a0,a1;
    const int R=row0+16*rt+fr;
    if constexpr(AG){ a0=gld(A+R*128+fg*16); a1=gld(A+R*128+64+fg*16); }
    else            { a0=fragld(A,R,fg*16);  a1=fragld(A,R,64+fg*16);  }
    #pragma unroll
    for(int n=0;n<4;n++){
      acc[rt][n]=MFMA16(a0,bf[2*n],acc[rt][n]);
      acc[rt][n]=MFMA16(a1,bf[2*n+1],acc[rt][n]);
    }
  }
}
__device__ __forceinline__ void zero2(f32x4 acc[2][4]){
  #pragma unroll
  for(int rt=0;rt<2;rt++)
    #pragma unroll
    for(int n=0;n<4;n++) acc[rt][n]=f32x4{0.f,0.f,0.f,0.f};
}
// store own 32 rows: C = ACT(acc + bz[col]); pi-packed cols, XOR rows, b64
template<int ACT>
__device__ __forceinline__ void st2_cb(char* C, const f32x4 acc[2][4], const float* bz,
                                       int fr, int fg, int row0){
  #pragma unroll
  for(int rt=0;rt<2;rt++)
  #pragma unroll
  for(int r=0;r<4;r++){
    const int R=row0+16*rt+4*fg+r;
    float v[4];
    #pragma unroll
    for(int n=0;n<4;n++) v[n]=actf<ACT>(acc[rt][n][r]+bz[n]);
    uint2 pk; pk.x=pack2(v[0],v[1]); pk.y=pack2(v[2],v[3]);
    *reinterpret_cast<uint2*>(C + R*128 + ((8*fr)^((R&7)<<4))) = pk;
  }
}
// per-ROW bias (d-fold), no activation
__device__ __forceinline__ void st2_rb(char* C, const f32x4 acc[2][4], const float* dbase,
                                       int fr, int fg, int row0){
  #pragma unroll
  for(int rt=0;rt<2;rt++)
  #pragma unroll
  for(int r=0;r<4;r++){
    const int R=row0+16*rt+4*fg+r;
    const float d=dbase[R];
    float v[4];
    #pragma unroll
    for(int n=0;n<4;n++) v[n]=acc[rt][n][r]+d;
    uint2 pk; pk.x=pack2(v[0],v[1]); pk.y=pack2(v[2],v[3]);
    *reinterpret_cast<uint2*>(C + R*128 + ((8*fr)^((R&7)<<4))) = pk;
  }
}

// MODE 0: P=softmax(S*SCALE). MODE 1: consensus mg (emits mb[2]). MODE 2: ~mb.
template<int MODE>
__device__ __forceinline__ void ssoft2(const char* Aq, const char* Bk, char* P,
                                       const float2* ra, const float4* zz,
                                       float cu, float cq, unsigned* mb,
                                       int fr, int fg, int row0){
  bf16x8 bf[8]; loadB_lds(Bk,bf,fr,fg);
  f32x4 acc[2][4]; zero2(acc);
  mm2<false>(Aq,bf,acc,fr,fg,row0);
  float rc[4];
  if constexpr(MODE==1){
    #pragma unroll
    for(int n=0;n<4;n++) rc[n]=ra[n*16+fr].x;
  }
  #pragma unroll
  for(int rt=0;rt<2;rt++){
    unsigned mbits=0;
    if constexpr(MODE==1){
      float aR[4],ucR[4],qtR[4]; bool gi[4];
      #pragma unroll
      for(int r=0;r<4;r++){
        const int R=row0+16*rt+4*fg+r;
        const float2 rv=ra[R];
        gi[r]=rv.x>rv.y; aR[r]=rv.y;
        const float4 z4=zz[R];
        ucR[r]=z4.x+cu; qtR[r]=z4.y+cq;
      }
      #pragma unroll
      for(int n=0;n<4;n++){
        #pragma unroll
        for(int r=0;r<4;r++){
          const bool mv=gi[r]||(rc[n]>aR[r]);
          if(mv) mbits|=1u<<(n*4+r);
          const float mf=mv?1.f:0.f;
          acc[rt][n][r]=(mf*(acc[rt][n][r]+ucR[r])+qtR[r])*SCALE;
        }
      }
      mb[rt]=mbits;
    } else if constexpr(MODE==2){
      mbits=mb[rt]^0xffffu;
      float ucR[4],qtR[4];
      #pragma unroll
      for(int r=0;r<4;r++){
        const float4 z4=zz[row0+16*rt+4*fg+r];
        ucR[r]=z4.z+cu; qtR[r]=z4.w+cq;
      }
      #pragma unroll
      for(int n=0;n<4;n++){
        #pragma unroll
        for(int r=0;r<4;r++){
          const float mf=((mbits>>(n*4+r))&1u)?1.f:0.f;
          acc[rt][n][r]=(mf*(acc[rt][n][r]+ucR[r])+qtR[r])*SCALE;
        }
      }
    }
    float mx[4];
    #pragma unroll
    for(int r=0;r<4;r++)
      mx[r]=fmaxf(fmaxf(acc[rt][0][r],acc[rt][1][r]),
                  fmaxf(acc[rt][2][r],acc[rt][3][r]));
    #pragma unroll
    for(int m=1;m<16;m<<=1){
      #pragma unroll
      for(int r=0;r<4;r++) mx[r]=fmaxf(mx[r],__shfl_xor(mx[r],m));
    }
    float sm[4]={0,0,0,0};
    #pragma unroll
    for(int n=0;n<4;n++){
      #pragma unroll
      for(int r=0;r<4;r++){
        float e;
        if constexpr(MODE==0) e=__expf((acc[rt][n][r]-mx[r])*SCALE);
        else e=__expf(acc[rt][n][r]-mx[r]);
        acc[rt][n][r]=e; sm[r]+=e;
      }
    }
    #pragma unroll
    for(int m=1;m<16;m<<=1){
      #pragma unroll
      for(int r=0;r<4;r++) sm[r]+=__shfl_xor(sm[r],m);
    }
    #pragma unroll
    for(int r=0;r<4;r++){
      const int R=row0+16*rt+4*fg+r;
      const float ri=1.f/sm[r];
      float v[4];
      #pragma unroll
      for(int n=0;n<4;n++){
        float e=acc[rt][n][r]*ri;
        if constexpr(MODE!=0) e=(mbits&(1u<<(n*4+r)))?e:0.f;
        v[n]=e;
      }
      uint2 pk; pk.x=pack2(v[0],v[1]); pk.y=pack2(v[2],v[3]);
      *reinterpret_cast<uint2*>(P + R*128 + ((8*fr)^((R&7)<<4))) = pk;
    }
  }
}

// park O=lrelu(oacc+e) into Buf own rows, fold into hacc via head MFMAs
__device__ __forceinline__ void park2(char* Buf, const f32x4 oacc[2][4],
                                      const float* ev, const char* hwb,
                                      f32x4* hacc, int fr, int fg, int row0){
  float bz[4];
  #pragma unroll
  for(int n=0;n<4;n++) bz[n]=ev[n*16+fr];
  st2_cb<1>(Buf,oacc,bz,fr,fg,row0);
  const bf16x8 h0=gld(hwb+fr*256+fg*16);
  const bf16x8 h1=gld(hwb+fr*256+64+fg*16);
  #pragma unroll
  for(int rt=0;rt<2;rt++){
    hacc[rt]=MFMA16(fragld(Buf,row0+16*rt+fr,fg*16),    h0, hacc[rt]);
    hacc[rt]=MFMA16(fragld(Buf,row0+16*rt+fr,64+fg*16), h1, hacc[rt]);
  }
}

__global__ __launch_bounds__(128,3) void rap_kernel(Params p){
  __shared__ __align__(16) char X[8192];
  __shared__ __align__(16) char Y[8192];
  __shared__ __align__(16) char Z[8192];
  __shared__ __align__(16) float2 ra_s[64];
  __shared__ __align__(16) float4 zz_s[64];
  const int t=threadIdx.x, l=t&63, fr=l&15, fg=l>>4, wv=t>>6;
  const int row0=32*wv;
  const int bi=blockIdx.x;
  const char* ws=p.ws;
  const float* VECF=(const float*)(ws+WS_VEC);
  const float4 scf=*(const float4*)(ws+WS_SC);   // c1, hbk1, c2, hbk2
  const float2* ra=ra_s;
  const float4* zz=zz_s;

  if(t<64){
    const float r0=p.rnd[bi*64+t];
    const float av=p.rnd[bi*64+p.idx[bi*64+t]];
    ra_s[t]=make_float2(r0,av);
  }
  // x staging: OWN 32 rows, pi+XOR, b128 stores (4 iters/thread)
  {
    const float* Gx=p.x+(size_t)bi*4096;
    #pragma unroll
    for(int j=0;j<4;j++){
      const int lf=j*64+l, R=row0+(lf>>3), k=lf&7;
      const float2 L0=*reinterpret_cast<const float2*>(Gx+R*64+2*k);
      const float2 L1=*reinterpret_cast<const float2*>(Gx+R*64+16+2*k);
      const float2 L2=*reinterpret_cast<const float2*>(Gx+R*64+32+2*k);
      const float2 L3=*reinterpret_cast<const float2*>(Gx+R*64+48+2*k);
      uint4 pk;
      pk.x=pack2(L0.x,L1.x); pk.y=pack2(L2.x,L3.x);
      pk.z=pack2(L0.y,L1.y); pk.w=pack2(L2.y,L3.y);
      *reinterpret_cast<uint4*>(X + R*128 + ((16*k)^((R&7)<<4)))=pk;
    }
  }
  bf16x8 bfv[8];
  float bz[4];
  f32x4 acc[2][4];
  unsigned mb[2]={0,0};
  // S1: E = lrelu(x@embed^T + eb) -> Y (own rows; X own-rows written by same wave)
  loadB_gl(ws+0*8192,bfv,fr,fg);
  #pragma unroll
  for(int n=0;n<4;n++) bz[n]=p.embed_b[n*16+fr];
  zero2(acc); mm2<false>(X,bfv,acc,fr,fg,row0);
  st2_cb<1>(Y,acc,bz,fr,fg,row0);
  // S2: T0' = E@M0 + m0 -> X (own rows)
  loadB_gl(ws+1*8192,bfv,fr,fg);
  #pragma unroll
  for(int n=0;n<4;n++) bz[n]=VECF[n*16+fr];
  zero2(acc); mm2<false>(Y,bfv,acc,fr,fg,row0);
  st2_cb<0>(X,acc,bz,fr,fg,row0);
  __syncthreads();                                   // BAR1: E + T0' full
  // S3: P = softmax(T0'@E^T * SCALE) in-place X (A own, B=Y full)
  ssoft2<0>(X,Y,X,nullptr,nullptr,0.f,0.f,mb,fr,fg,row0);
  // S4: VOT = Wvo@E^T -> Z (A global own rows, B=Y full)
  loadB_lds(Y,bfv,fr,fg);
  zero2(acc); mm2<true>(ws+2*8192,bfv,acc,fr,fg,row0);
  { const float bz0[4]={0,0,0,0}; st2_cb<0>(Z,acc,bz0,fr,fg,row0); }
  __syncthreads();                                   // BAR2: VOT full (E dead)
  // S5: ATT = tanh(P@VOT^T + cc) -> Y (own rows; B=Z full)
  loadB_lds(Z,bfv,fr,fg);
  #pragma unroll
  for(int n=0;n<4;n++) bz[n]=VECF[64+n*16+fr];
  zero2(acc); mm2<false>(X,bfv,acc,fr,fg,row0);
  st2_cb<2>(Y,acc,bz,fr,fg,row0);
  // S6: T1' = ATT@M1 + wt1 -> X ; zz = ATT@Nv (own rows; A=Y own, just written)
  {
    loadB_gl(ws+3*8192,bfv,fr,fg);
    const bf16x8 nv0=gld(ws+WS_NV+fr*128+fg*16);
    const bf16x8 nv1=gld(ws+WS_NV+fr*128+64+fg*16);
    #pragma unroll
    for(int n=0;n<4;n++) bz[n]=VECF[128+n*16+fr];
    zero2(acc);
    #pragma unroll
    for(int rt=0;rt<2;rt++){
      const bf16x8 a0=fragld(Y,row0+16*rt+fr,fg*16);
      const bf16x8 a1=fragld(Y,row0+16*rt+fr,64+fg*16);
      #pragma unroll
      for(int n=0;n<4;n++){
        acc[rt][n]=MFMA16(a0,bfv[2*n],acc[rt][n]);
        acc[rt][n]=MFMA16(a1,bfv[2*n+1],acc[rt][n]);
      }
      f32x4 za={0,0,0,0};
      za=MFMA16(a0,nv0,za); za=MFMA16(a1,nv1,za);
      if(fr<4){
        #pragma unroll
        for(int r=0;r<4;r++)
          reinterpret_cast<float*>(&zz_s[row0+16*rt+4*fg+r])[fr]=za[r];
      }
    }
    st2_cb<0>(X,acc,bz,fr,fg,row0);
  }
  __syncthreads();                                   // BAR3: ATT + zz + ra full
  // S7: P1 = cons-softmax(T1'@ATT^T) in-place X (emits mb)
  ssoft2<1>(X,Y,X,ra,zz,scf.x,scf.y,mb,fr,fg,row0);
  // S7b: VMO1T = Nw1@ATT^T + d1 -> Z (A global own rows, B=Y full)
  loadB_lds(Y,bfv,fr,fg);
  zero2(acc); mm2<true>(ws+4*8192,bfv,acc,fr,fg,row0);
  st2_rb(Z,acc,VECF+256,fr,fg,row0);
  __syncthreads();                                   // BAR4: VMO1T full
  f32x4 hacc[2]={{0,0,0,0},{0,0,0,0}};
  // S8: o1acc = P1@VMO1T^T ; park O1 -> X own rows; fold hacc (HW cols 0-63)
  loadB_lds(Z,bfv,fr,fg);
  zero2(acc); mm2<false>(X,bfv,acc,fr,fg,row0);
  park2(X,acc,VECF+320,ws+WS_HW,hacc,fr,fg,row0);
  // S9: T2' = ATT@M2 + wt2 -> X (own rows; O1 already consumed)
  loadB_gl(ws+5*8192,bfv,fr,fg);
  #pragma unroll
  for(int n=0;n<4;n++) bz[n]=VECF[192+n*16+fr];
  zero2(acc); mm2<false>(Y,bfv,acc,fr,fg,row0);
  st2_cb<0>(X,acc,bz,fr,fg,row0);
  // S10: P2 = cons-softmax(T2'@ATT^T, ~mb) in-place X (B=Y unchanged)
  ssoft2<2>(X,Y,X,ra,zz,scf.z,scf.w,mb,fr,fg,row0);
  __syncthreads();                                   // BAR5: all S8 Z-reads done
  // S11: VMO2T = Nw2@ATT^T + d2 -> Z (A global own rows, B=Y full, last Y use)
  loadB_lds(Y,bfv,fr,fg);
  zero2(acc); mm2<true>(ws+6*8192,bfv,acc,fr,fg,row0);
  st2_rb(Z,acc,VECF+384,fr,fg,row0);
  __syncthreads();                                   // BAR6: VMO2T full, Y free
  // S12: o2acc = P2@VMO2T^T ; park O2 -> Y own rows; fold hacc (HW cols 64-127)
  loadB_lds(Z,bfv,fr,fg);
  zero2(acc); mm2<false>(X,bfv,acc,fr,fg,row0);
  park2(Y,acc,VECF+448,ws+WS_HW+128,hacc,fr,fg,row0);
  // out: row R = agent (own), col fr = out-dim
  {
    const float bzo=(fr<8)?p.mean_b[fr]:p.ls_b[fr-8];
    #pragma unroll
    for(int rt=0;rt<2;rt++)
    #pragma unroll
    for(int r=0;r<4;r++){
      const int R=row0+16*rt+4*fg+r;
      const long base=((long)bi*64+R)*8;
      float v=hacc[rt][r]+bzo;
      if(fr<8) p.out[base+fr]=v;
      else{
        v=fminf(fmaxf(v,-20.f),2.f);
        p.out[p.std_off+base+fr-8]=__expf(v);
      }
    }
  }
}

} // namespace

extern "C" void kernel_launch(void* const* d_in, const int* in_sizes, int n_in,
                              void* d_out, int out_size, void* d_ws, size_t ws_size,
                              hipStream_t stream){
  (void)n_in; (void)out_size; (void)ws_size;
  PrepP q;
  q.embed_w=(const float*)d_in[3];
  q.ia_wq=(const float*)d_in[5];  q.ia_bq=(const float*)d_in[6];
  q.ia_wk=(const float*)d_in[7];
  q.ia_wv=(const float*)d_in[9];  q.ia_bv=(const float*)d_in[10];
  q.ia_wo=(const float*)d_in[11]; q.ia_bo=(const float*)d_in[12];
  q.c1_wq=(const float*)d_in[13]; q.c1_bq=(const float*)d_in[14];
  q.c1_wk=(const float*)d_in[15]; q.c1_bk=(const float*)d_in[16];
  q.c1_wv=(const float*)d_in[17]; q.c1_bv=(const float*)d_in[18];
  q.c1_wo=(const float*)d_in[19]; q.c1_bo=(const float*)d_in[20];
  q.c2_wq=(const float*)d_in[21]; q.c2_bq=(const float*)d_in[22];
  q.c2_wk=(const float*)d_in[23]; q.c2_bk=(const float*)d_in[24];
  q.c2_wv=(const float*)d_in[25]; q.c2_bv=(const float*)d_in[26];
  q.c2_wo=(const float*)d_in[27]; q.c2_bo=(const float*)d_in[28];
  q.msg_w=(const float*)d_in[29]; q.msg_b=(const float*)d_in[30];
  q.st_w =(const float*)d_in[31]; q.st_b =(const float*)d_in[32];
  q.mean_w=(const float*)d_in[33]; q.ls_w=(const float*)d_in[35];
  q.ws=(char*)d_ws;
  prep_kernel<<<dim3(7), dim3(256), 0, stream>>>(q);

  Params p;
  p.x  =(const float*)d_in[0];
  p.rnd=(const float*)d_in[1];
  p.idx=(const int*)  d_in[2];
  p.embed_b=(const float*)d_in[4];
  p.mean_b =(const float*)d_in[34];
  p.ls_b   =(const float*)d_in[36];
  p.ws=(const char*)d_ws;
  p.out=(float*)d_out;
  const int Bb=in_sizes[0]/4096;   // x is [B,64,64]
  p.std_off=Bb*64*8;
  rap_kernel<<<dim3(Bb), dim3(128), 0, stream>>>(p);
}